// Round 1
// baseline (93.612 us; speedup 1.0000x reference)
//
#include <hip/hip_runtime.h>
#include <math.h>

// x[N,D] f32, w[D,1] f32. a=sigmoid(x@w) in (0,1), b=cumsum(a), idx=floor(b)
// non-decreasing with steps in {0,1}; bins never skip (a<1 strictly, and the
// f32 rounding window at b~4096 is +-ulp/2 ~ 2.4e-4 so floor can't jump 2).
// Column i contributes mainv[i] to row idx[i], crossv[i] to row idx[i]-1.
// Row r's main columns = [rowptr[r], rowptr[r+1]); its cross column is
// rowptr[r+1] (first column of row r+1), if < N.
//
// K1: 4 row-dots per 256-thread block -> a[]; per-block f64 partial sums
//     (no atomics, no memset: every slot written each call); rowptr defaults.
// K2: 32 blocks x 256 threads: two-level parallel f64 scan (256 group sums of
//     32 columns -> wave scan; within-wave scan of a) -> mainv/crossv +
//     rowptr crossing scatters.
// K3: ONE WAVE per row (2048 blocks x 4 waves). Each lane owns 4 float4
//     chunks of the row; 2-column unroll with UNCONDITIONAL weighted loads
//     (no per-column skip branch) -> 8-16 loads in flight per wave instead
//     of the old 1-in-flight serialized {load w -> branch -> load x} chain.
//     Skipped-tiny-weight reads are LLC hits (x is re-resident after K1), so
//     the extra ~10 MB of LLC traffic is far cheaper than the branch stalls.

__global__ __launch_bounds__(256) void dot_sigmoid_kernel(
    const float* __restrict__ x, const float* __restrict__ w,
    float* __restrict__ a, double* __restrict__ blocksum,
    int* __restrict__ rowptr, int N, int D) {
  __shared__ float was[4];
  int t = threadIdx.x;
  int lane = t & 63;
  int wave = t >> 6;
  int row = blockIdx.x * 4 + wave;
  const float4* xr = reinterpret_cast<const float4*>(x + (size_t)row * D);
  const float4* w4 = reinterpret_cast<const float4*>(w);
  float acc = 0.f;
  int nv = D >> 2;  // 256
  for (int j = lane; j < nv; j += 64) {
    float4 xv = xr[j];
    float4 wv = w4[j];
    acc = fmaf(xv.x, wv.x, acc);
    acc = fmaf(xv.y, wv.y, acc);
    acc = fmaf(xv.z, wv.z, acc);
    acc = fmaf(xv.w, wv.w, acc);
  }
#pragma unroll
  for (int off = 32; off > 0; off >>= 1) acc += __shfl_down(acc, off, 64);
  if (lane == 0) {
    float av = 1.0f / (1.0f + expf(-acc));
    a[row] = av;
    was[wave] = av;
  }
  int gtid = blockIdx.x * 256 + t;
  if (gtid <= N) rowptr[gtid] = N;  // defaults; k2 scatters crossings later
  __syncthreads();
  if (t == 0)
    blocksum[blockIdx.x] =
        (double)was[0] + (double)was[1] + (double)was[2] + (double)was[3];
}

// 32 blocks x 256 threads; block b owns columns [256b, 256b+256).
__global__ __launch_bounds__(256) void scan_emit_kernel(
    const float* __restrict__ a, const double* __restrict__ blocksum,
    float* __restrict__ mainv, float* __restrict__ crossv,
    int* __restrict__ rowptr, int N) {
  __shared__ double sg[256];  // exclusive group prefixes (group = 32 columns)
  __shared__ double wtot[4];
  int b = blockIdx.x;
  int t = threadIdx.x;
  int lane = t & 63;
  int wid = t >> 6;

  // group t = blocksums [8t, 8t+8) = columns [32t, 32t+32)
  double g = 0.0;
#pragma unroll
  for (int j = 0; j < 8; ++j) g += blocksum[8 * t + j];
  double vg = g;  // inclusive wave scan of group sums
  for (int off = 1; off < 64; off <<= 1) {
    double n = __shfl_up(vg, off, 64);
    if (lane >= off) vg += n;
  }
  if (lane == 63) wtot[wid] = vg;
  __syncthreads();
  double wb = 0.0;
  for (int q = 0; q < wid; ++q) wb += wtot[q];
  sg[t] = wb + vg - g;  // exclusive prefix of group t over all N columns
  __syncthreads();

  // per-column: exclusive prefix = sg[group] + within-group f64 scan of a
  int i = b * 256 + t;
  float ai = a[i];
  double va = (double)ai;  // inclusive wave scan of a
  for (int off = 1; off < 64; off <<= 1) {
    double n = __shfl_up(va, off, 64);
    if (lane >= off) va += n;
  }
  double E = va - (double)ai;          // exclusive prefix within wave
  int g0 = lane & ~31;                 // group start lane (0 or 32)
  double Eg0 = __shfl(E, g0, 64);
  int gg = 8 * b + (t >> 5);           // global group index of column i
  double prevbd = sg[gg] + (E - Eg0);
  double bd = prevbd + (double)ai;
  float bf = (float)bd;
  float pf = (float)prevbd;
  int k = (int)floorf(bf);
  int kp = (int)floorf(pf);
  float frac = bf - (float)k;
  bool same = (k == kp);
  mainv[i] = same ? ai : frac;
  crossv[i] = same ? 0.f : (ai - frac);
  if (!same) rowptr[k] = i;  // crossings have k>=1; unique per row
  if (b == 0 && t == 0) rowptr[0] = 0;  // row 0 starts at column 0
}

// One WAVE per row: blockIdx.x*4+wave = row. Each lane owns 4 float4 chunks.
// 2-column unroll, unconditional weighted loads -> deep load pipelining.
__global__ __launch_bounds__(256) void out_kernel(
    const float* __restrict__ x, const float* __restrict__ mainv,
    const float* __restrict__ crossv, const int* __restrict__ rowptr,
    float* __restrict__ out, int N, int D) {
  int t = threadIdx.x;
  int lane = t & 63;
  int wave = t >> 6;
  int r = blockIdx.x * 4 + wave;
  int nv = D >> 2;  // float4 per row (256)
  int q = nv >> 2;  // per-lane float4 stride (64)
  int s0 = rowptr[r];
  int s1 = rowptr[r + 1];
  const float4* xb = reinterpret_cast<const float4*>(x) + lane;
  float4 acc0 = make_float4(0.f, 0.f, 0.f, 0.f);
  float4 acc1 = acc0, acc2 = acc0, acc3 = acc0;
#define FMA4(A, W, V)      \
  A.x = fmaf(W, V.x, A.x); \
  A.y = fmaf(W, V.y, A.y); \
  A.z = fmaf(W, V.z, A.z); \
  A.w = fmaf(W, V.w, A.w);
  int i = s0;
  for (; i + 2 <= s1; i += 2) {  // main columns, 2 at a time (8 loads in flight)
    float w0 = mainv[i];
    float w1 = mainv[i + 1];
    const float4* p0 = xb + (size_t)i * nv;
    const float4* p1 = p0 + nv;
    float4 a0 = p0[0], a1 = p0[q], a2 = p0[2 * q], a3 = p0[3 * q];
    float4 b0 = p1[0], b1 = p1[q], b2 = p1[2 * q], b3 = p1[3 * q];
    FMA4(acc0, w0, a0);
    FMA4(acc1, w0, a1);
    FMA4(acc2, w0, a2);
    FMA4(acc3, w0, a3);
    FMA4(acc0, w1, b0);
    FMA4(acc1, w1, b1);
    FMA4(acc2, w1, b2);
    FMA4(acc3, w1, b3);
  }
  if (i < s1) {  // odd tail column
    float w0 = mainv[i];
    const float4* p0 = xb + (size_t)i * nv;
    float4 a0 = p0[0], a1 = p0[q], a2 = p0[2 * q], a3 = p0[3 * q];
    FMA4(acc0, w0, a0);
    FMA4(acc1, w0, a1);
    FMA4(acc2, w0, a2);
    FMA4(acc3, w0, a3);
  }
  if (s1 < N) {  // first column of row r+1 crosses back into row r
    float wc = crossv[s1];
    const float4* p0 = xb + (size_t)s1 * nv;
    float4 a0 = p0[0], a1 = p0[q], a2 = p0[2 * q], a3 = p0[3 * q];
    FMA4(acc0, wc, a0);
    FMA4(acc1, wc, a1);
    FMA4(acc2, wc, a2);
    FMA4(acc3, wc, a3);
  }
#undef FMA4
  float4* ob = reinterpret_cast<float4*>(out + (size_t)r * D) + lane;
  ob[0] = acc0;
  ob[q] = acc1;
  ob[2 * q] = acc2;
  ob[3 * q] = acc3;
}

extern "C" void kernel_launch(void* const* d_in, const int* in_sizes, int n_in,
                              void* d_out, int out_size, void* d_ws, size_t ws_size,
                              hipStream_t stream) {
  const float* x = (const float*)d_in[0];
  const float* w = (const float*)d_in[1];
  float* out = (float*)d_out;
  int D = in_sizes[1];      // 1024
  int N = in_sizes[0] / D;  // 8192

  float* a = (float*)d_ws;
  float* mainv = a + N;
  float* crossv = mainv + N;
  int* rowptr = (int*)(crossv + N);  // N+1 entries
  double* blocksum = (double*)(((uintptr_t)(rowptr + N + 1) + 15) & ~15ull);
  // blocksum: N/4 doubles, every slot written by k1 each call (poison-safe)

  hipLaunchKernelGGL(dot_sigmoid_kernel, dim3(N / 4), dim3(256), 0, stream,
                     x, w, a, blocksum, rowptr, N, D);
  hipLaunchKernelGGL(scan_emit_kernel, dim3(N / 256), dim3(256), 0, stream,
                     a, blocksum, mainv, crossv, rowptr, N);
  hipLaunchKernelGGL(out_kernel, dim3(N / 4), dim3(256), 0, stream,
                     x, mainv, crossv, rowptr, out, N, D);
}